// Round 1
// baseline (143.862 us; speedup 1.0000x reference)
//
#include <hip/hip_runtime.h>
#include <hip/hip_bf16.h>

// Pairwise distances over edges:
//   d[e] = || R[idx_i[e]] - R[idx_j[e]] ||_2
// R: [N_ATOMS, 3] float32 (1.2 MB -> lives in L2), idx: int32 per harness,
// out: [E] float32.
//
// Memory-bound streaming kernel: int4 index loads, float4 stores, gathers
// served from cache. 4 edges per thread.

__global__ __launch_bounds__(256) void pairwise_dist_kernel(
    const float* __restrict__ R,
    const int* __restrict__ idx_i,
    const int* __restrict__ idx_j,
    float* __restrict__ out,
    int n_edges)
{
    const int quad = blockIdx.x * blockDim.x + threadIdx.x;  // which group of 4 edges
    const int n_quads = n_edges >> 2;

    if (quad < n_quads) {
        const int4 a = ((const int4*)idx_i)[quad];
        const int4 b = ((const int4*)idx_j)[quad];

        float4 o;
        {
            const float* pa = R + 3 * (long)a.x;
            const float* pb = R + 3 * (long)b.x;
            float dx = pa[0] - pb[0], dy = pa[1] - pb[1], dz = pa[2] - pb[2];
            o.x = sqrtf(dx * dx + dy * dy + dz * dz);
        }
        {
            const float* pa = R + 3 * (long)a.y;
            const float* pb = R + 3 * (long)b.y;
            float dx = pa[0] - pb[0], dy = pa[1] - pb[1], dz = pa[2] - pb[2];
            o.y = sqrtf(dx * dx + dy * dy + dz * dz);
        }
        {
            const float* pa = R + 3 * (long)a.z;
            const float* pb = R + 3 * (long)b.z;
            float dx = pa[0] - pb[0], dy = pa[1] - pb[1], dz = pa[2] - pb[2];
            o.z = sqrtf(dx * dx + dy * dy + dz * dz);
        }
        {
            const float* pa = R + 3 * (long)a.w;
            const float* pb = R + 3 * (long)b.w;
            float dx = pa[0] - pb[0], dy = pa[1] - pb[1], dz = pa[2] - pb[2];
            o.w = sqrtf(dx * dx + dy * dy + dz * dz);
        }
        ((float4*)out)[quad] = o;
    }

    // Tail: edges not covered by the quad loop (n_edges % 4).
    const int tail_start = n_quads << 2;
    const int tail = n_edges - tail_start;
    if (tail > 0 && quad < tail) {
        const int e = tail_start + quad;
        const int ia = idx_i[e], ib = idx_j[e];
        const float* pa = R + 3 * (long)ia;
        const float* pb = R + 3 * (long)ib;
        float dx = pa[0] - pb[0], dy = pa[1] - pb[1], dz = pa[2] - pb[2];
        out[e] = sqrtf(dx * dx + dy * dy + dz * dz);
    }
}

extern "C" void kernel_launch(void* const* d_in, const int* in_sizes, int n_in,
                              void* d_out, int out_size, void* d_ws, size_t ws_size,
                              hipStream_t stream)
{
    const float* R     = (const float*)d_in[0];
    const int*   idx_i = (const int*)d_in[1];
    const int*   idx_j = (const int*)d_in[2];
    float*       out   = (float*)d_out;

    const int n_edges = in_sizes[1];            // 6,400,000
    const int n_quads = (n_edges + 3) >> 2;
    const int block   = 256;
    const int grid    = (n_quads + block - 1) / block;

    pairwise_dist_kernel<<<grid, block, 0, stream>>>(R, idx_i, idx_j, out, n_edges);
}